// Round 14
// baseline (168.138 us; speedup 1.0000x reference)
//
#include <hip/hip_runtime.h>

#define NB 128
#define NC 12
#define NL 1024
#define NDIL 7
#define NDIV 2
#define NH 32
#define NK 8
#define NKSZ 9
#define NNCP 6
#define OUTPB (NDIL*NDIV*2*NH*NK)   // 7168

// LDS: [Z0 256][g0 1024][Z1 256][g1 1024][Z2 256][g2 1024][Z3 256][g3 1024][Z4 256]
// zero strips shared between adjacent waves' pads; wave w zeroes strips w and w+1.
#define SER_STRIDE 1280
#define LDS_FLOATS (4*SER_STRIDE + 256)   // 5376 floats = 21504 B

typedef float f2 __attribute__((ext_vector_type(2)));

__device__ __forceinline__ float4 ld4(const float* p) { return *(const float4*)p; }

__device__ __forceinline__ float sgpr_f(float v) {
    return __int_as_float(__builtin_amdgcn_readfirstlane(__float_as_int(v)));
}

// packed fp32 FMA, weight = LOW half of SGPR pair broadcast to both halves
__device__ __forceinline__ void pkfma_lo(f2 &acc, f2 ws, f2 v) {
    asm("v_pk_fma_f32 %0, %1, %2, %0 op_sel:[0,0,0] op_sel_hi:[0,1,1]"
        : "+v"(acc) : "s"(ws), "v"(v));
}
// packed fp32 FMA, weight = HIGH half of SGPR pair broadcast to both halves
__device__ __forceinline__ void pkfma_hi(f2 &acc, f2 ws, f2 v) {
    asm("v_pk_fma_f32 %0, %1, %2, %0 op_sel:[1,0,0] op_sel_hi:[1,1,1]"
        : "+v"(acc) : "s"(ws), "v"(v));
}
__device__ __forceinline__ f2 pkmul_lo(f2 ws, f2 v) {
    f2 d;
    asm("v_pk_mul_f32 %0, %1, %2 op_sel:[0,0] op_sel_hi:[0,1]"
        : "=v"(d) : "s"(ws), "v"(v));
    return d;
}
__device__ __forceinline__ f2 pkmul_hi(f2 ws, f2 v) {
    f2 d;
    asm("v_pk_mul_f32 %0, %1, %2 op_sel:[1,0] op_sel_hi:[1,1]"
        : "=v"(d) : "s"(ws), "v"(v));
    return d;
}

template<int CTRL, int RM>
__device__ __forceinline__ float dppadd_f(float x) {
    int t = __builtin_amdgcn_update_dpp(0, __float_as_int(x), CTRL, RM, 0xf, false);
    return x + __int_as_float(t);
}
template<int CTRL, int RM>
__device__ __forceinline__ unsigned dppadd_u(unsigned x) {
    int t = __builtin_amdgcn_update_dpp(0, (int)x, CTRL, RM, 0xf, false);
    return x + (unsigned)t;
}
// full-wave sum; result valid on lane 63
#define RSUM_F(x) { x = dppadd_f<0x111,0xf>(x); x = dppadd_f<0x112,0xf>(x); \
                    x = dppadd_f<0x114,0xf>(x); x = dppadd_f<0x118,0xf>(x); \
                    x = dppadd_f<0x142,0xa>(x); x = dppadd_f<0x143,0xc>(x); }
#define RSUM_U(x) { x = dppadd_u<0x111,0xf>(x); x = dppadd_u<0x112,0xf>(x); \
                    x = dppadd_u<0x114,0xf>(x); x = dppadd_u<0x118,0xf>(x); \
                    x = dppadd_u<0x142,0xa>(x); x = dppadd_u<0x143,0xc>(x); }

// weight flat index f = k*NKSZ+t -> SGPR pair wp[f>>1], half f&1 (folds at unroll)
#define PKFMA(acc, f, v)  { if (((f) & 1) == 0) pkfma_lo(acc, wp[(f)>>1], v); \
                            else               pkfma_hi(acc, wp[(f)>>1], v); }
#define PKMUL(d, f, v)    { if (((f) & 1) == 0) d = pkmul_lo(wp[(f)>>1], v);  \
                            else               d = pkmul_hi(wp[(f)>>1], v); }
#define WSC(f) ((((f) & 1) == 0) ? wp[(f)>>1].x : wp[(f)>>1].y)

// argbin over packed accumulators; y-half gated by OK1
#define ARGBIN2(AC, OK1)                                                  \
    {                                                                     \
        float mx0 = fmaxf(fmaxf(AC[0].x, AC[1].x), AC[2].x);              \
        mx0 = fmaxf(fmaxf(mx0, AC[3].x), AC[4].x);                        \
        mx0 = fmaxf(fmaxf(mx0, AC[5].x), AC[6].x);                        \
        mx0 = fmaxf(mx0, AC[7].x);                                        \
        float mn0 = fminf(fminf(AC[0].x, AC[1].x), AC[2].x);              \
        mn0 = fminf(fminf(mn0, AC[3].x), AC[4].x);                        \
        mn0 = fminf(fminf(mn0, AC[5].x), AC[6].x);                        \
        mn0 = fminf(mn0, AC[7].x);                                        \
        _Pragma("unroll")                                                 \
        for (int k = 0; k < NK; ++k) {                                    \
            cm[k] += (AC[k].x == mx0) ? AC[k].x : 0.f;                    \
            cn[k] += (AC[k].x == mn0) ? 1u : 0u;                          \
        }                                                                 \
        float mx1 = fmaxf(fmaxf(AC[0].y, AC[1].y), AC[2].y);              \
        mx1 = fmaxf(fmaxf(mx1, AC[3].y), AC[4].y);                        \
        mx1 = fmaxf(fmaxf(mx1, AC[5].y), AC[6].y);                        \
        mx1 = fmaxf(mx1, AC[7].y);                                        \
        float mn1 = fminf(fminf(AC[0].y, AC[1].y), AC[2].y);              \
        mn1 = fminf(fminf(mn1, AC[3].y), AC[4].y);                        \
        mn1 = fminf(fminf(mn1, AC[5].y), AC[6].y);                        \
        mn1 = fminf(mn1, AC[7].y);                                        \
        if (OK1) {                                                        \
            _Pragma("unroll")                                             \
            for (int k = 0; k < NK; ++k) {                                \
                cm[k] += (AC[k].y == mx1) ? AC[k].y : 0.f;                \
                cn[k] += (AC[k].y == mn1) ? 1u : 0u;                      \
            }                                                             \
        }                                                                 \
    }

// conv + argbin over 1024 positions (2/lane/chunk), compile-time dilation D.
// Inner product via v_pk_fma_f32: both positions of the pair per instruction.
template<int D>
__device__ __forceinline__ void conv_body(const float* __restrict__ bp0,
                                          const f2 (&wp)[36], bool okl,
                                          float (&cm)[NK], unsigned (&cn)[NK]) {
    if constexpr (D == 1) {
        const float* bp = bp0 - 4;
        for (int c = 0; c < 8; ++c, bp += 128) {
            f2 q0 = *(const f2*)(bp);
            f2 q1 = *(const f2*)(bp + 2);
            f2 q2 = *(const f2*)(bp + 4);
            f2 q3 = *(const f2*)(bp + 6);
            f2 q4 = *(const f2*)(bp + 8);
            f2 ac[NK];
            // even taps: aligned pairs -> packed
            #pragma unroll
            for (int k = 0; k < NK; ++k) PKMUL(ac[k], k*NKSZ+0, q0);
            #pragma unroll
            for (int k = 0; k < NK; ++k) PKFMA(ac[k], k*NKSZ+2, q1);
            #pragma unroll
            for (int k = 0; k < NK; ++k) PKFMA(ac[k], k*NKSZ+4, q2);
            #pragma unroll
            for (int k = 0; k < NK; ++k) PKFMA(ac[k], k*NKSZ+6, q3);
            #pragma unroll
            for (int k = 0; k < NK; ++k) PKFMA(ac[k], k*NKSZ+8, q4);
            // odd taps: straddle pair alignment -> scalar halves
            #pragma unroll
            for (int k = 0; k < NK; ++k) {
                ac[k].x = fmaf(WSC(k*NKSZ+1), q0.y, ac[k].x);
                ac[k].y = fmaf(WSC(k*NKSZ+1), q1.x, ac[k].y);
                ac[k].x = fmaf(WSC(k*NKSZ+3), q1.y, ac[k].x);
                ac[k].y = fmaf(WSC(k*NKSZ+3), q2.x, ac[k].y);
                ac[k].x = fmaf(WSC(k*NKSZ+5), q2.y, ac[k].x);
                ac[k].y = fmaf(WSC(k*NKSZ+5), q3.x, ac[k].y);
                ac[k].x = fmaf(WSC(k*NKSZ+7), q3.y, ac[k].x);
                ac[k].y = fmaf(WSC(k*NKSZ+7), q4.x, ac[k].y);
            }
            ARGBIN2(ac, (c != 7) || okl);
        }
    } else {
        const float* bp = bp0 - 4*D;
        for (int c = 0; c < 8; ++c, bp += 128) {
            f2 r[NKSZ];
            #pragma unroll
            for (int t = 0; t < NKSZ; ++t)
                r[t] = *(const f2*)(bp + t*D);   // imm-foldable offsets
            f2 ac[NK];
            #pragma unroll
            for (int k = 0; k < NK; ++k) PKMUL(ac[k], k*NKSZ+0, r[0]);
            #pragma unroll
            for (int t = 1; t < NKSZ; ++t)
                #pragma unroll
                for (int k = 0; k < NK; ++k) PKFMA(ac[k], k*NKSZ+t, r[t]);
            ARGBIN2(ac, (c != 7) || okl);
        }
    }
}

__global__ __launch_bounds__(256) void hydra_kernel(
    const float* __restrict__ X,   // [B, C, L]
    const float* __restrict__ W,   // [NDIL, NDIV, K*H, 1, KSZ]
    const int*   __restrict__ I,   // [NDIL, NDIV, H, NCP]
    float*       __restrict__ out) // [B, 28*H*K]
{
    __shared__ float lds[LDS_FLOATS];

    const int bid = blockIdx.x;
    const int h4 = bid & 7;
    const int dj = (bid >> 3) % 14;
    const int b  = (bid >> 3) / 14;
    const int di = dj >> 1;
    const int j  = dj & 1;

    const int tid  = threadIdx.x;
    const int lane = tid & 63;
    const int wid  = __builtin_amdgcn_readfirstlane(tid >> 6);
    const int h    = h4 * 4 + wid;            // wave-uniform
    const int Sw   = 256 + wid * SER_STRIDE;  // this wave's series base

    // zero own pad strips (w and w+1); neighbor duplicate zero-writes benign
    #pragma unroll
    for (int z = 0; z < 2; ++z) {
        float4 zz; zz.x = 0.f; zz.y = 0.f; zz.z = 0.f; zz.w = 0.f;
        *(float4*)(lds + (wid + z) * SER_STRIDE + 4 * lane) = zz;
    }

    // --- gather-sum into this wave's series (wave-private, no barrier) ----
    const int* idx = I + ((di*NDIV + j)*NH + h)*NNCP;
    const float* xb = X + (size_t)b * NC * NL;
    const float* p0 = xb + idx[0]*NL;
    const float* p1 = xb + idx[1]*NL;
    const float* p2 = xb + idx[2]*NL;
    const float* p3 = xb + idx[3]*NL;
    const float* p4 = xb + idx[4]*NL;
    const float* p5 = xb + idx[5]*NL;

    if (j == 0) {
        #pragma unroll
        for (int c = 0; c < 4; ++c) {
            const int e = 256*c + 4*lane;
            float4 v0 = ld4(p0+e), v1 = ld4(p1+e), v2 = ld4(p2+e);
            float4 v3 = ld4(p3+e), v4 = ld4(p4+e), v5 = ld4(p5+e);
            float4 s;
            s.x = v0.x+v1.x+v2.x+v3.x+v4.x+v5.x;
            s.y = v0.y+v1.y+v2.y+v3.y+v4.y+v5.y;
            s.z = v0.z+v1.z+v2.z+v3.z+v4.z+v5.z;
            s.w = v0.w+v1.w+v2.w+v3.w+v4.w+v5.w;
            *(float4*)(lds + Sw + e) = s;
        }
    } else {
        // diff-of-gather == gather-of-diff (linearity)
        float4 sa[4];
        #pragma unroll
        for (int c = 0; c < 4; ++c) {
            const int e = 256*c + 4*lane;
            float4 v0 = ld4(p0+e), v1 = ld4(p1+e), v2 = ld4(p2+e);
            float4 v3 = ld4(p3+e), v4 = ld4(p4+e), v5 = ld4(p5+e);
            sa[c].x = v0.x+v1.x+v2.x+v3.x+v4.x+v5.x;
            sa[c].y = v0.y+v1.y+v2.y+v3.y+v4.y+v5.y;
            sa[c].z = v0.z+v1.z+v2.z+v3.z+v4.z+v5.z;
            sa[c].w = v0.w+v1.w+v2.w+v3.w+v4.w+v5.w;
        }
        #pragma unroll
        for (int c = 0; c < 4; ++c) {
            const float nxt = (c < 3) ? __shfl(sa[(c+1) & 3].x, 0, 64) : 0.f;
            const float sh  = __shfl_down(sa[c].x, 1, 64);
            const float Se4 = (lane == 63) ? nxt : sh;
            float4 df;
            df.x = sa[c].y - sa[c].x;
            df.y = sa[c].z - sa[c].y;
            df.z = sa[c].w - sa[c].z;
            df.w = Se4 - sa[c].w;
            if (c == 3 && lane == 63) df.w = 0.f;   // diff series: slot 1023 = 0
            const int e = 256*c + 4*lane;
            *(float4*)(lds + Sw + e) = df;
        }
    }

    // --- weights: SGPR pairs (wave-uniform h), accessed via op_sel --------
    f2 wp[36];
    {
        const float* Wp = W + (size_t)((di*NDIV + j)*(NK*NH) + h*NK) * NKSZ;
        #pragma unroll
        for (int i = 0; i < 18; ++i) {
            float4 v = ld4(Wp + 4*i);
            wp[2*i].x   = sgpr_f(v.x); wp[2*i].y   = sgpr_f(v.y);
            wp[2*i+1].x = sgpr_f(v.z); wp[2*i+1].y = sgpr_f(v.w);
        }
    }

    float    cm[NK];
    unsigned cn[NK];
    #pragma unroll
    for (int k = 0; k < NK; ++k) { cm[k] = 0.f; cn[k] = 0u; }

    const float* bp0 = lds + Sw + 2*lane;        // pos-pair base
    const bool   okl = (j == 0) || (lane != 63); // only pos 1023/j=1 invalid

    switch (di) {
        case 0: conv_body<1>( bp0, wp, okl, cm, cn); break;
        case 1: conv_body<2>( bp0, wp, okl, cm, cn); break;
        case 2: conv_body<4>( bp0, wp, okl, cm, cn); break;
        case 3: conv_body<8>( bp0, wp, okl, cm, cn); break;
        case 4: conv_body<16>(bp0, wp, okl, cm, cn); break;
        case 5: conv_body<32>(bp0, wp, okl, cm, cn); break;
        default: conv_body<64>(bp0, wp, okl, cm, cn); break;
    }

    // pack counts (each half-word sum <= 1024, no carry crossing)
    unsigned cp[4];
    #pragma unroll
    for (int i = 0; i < 4; ++i) cp[i] = cn[2*i] | (cn[2*i+1] << 16);

    // DPP wave sums (VALU-only), results land on lane 63
    #pragma unroll
    for (int k = 0; k < NK; ++k) RSUM_F(cm[k]);
    #pragma unroll
    for (int i = 0; i < 4; ++i) RSUM_U(cp[i]);

    // lane 63 writes this wave's 16 outputs directly (no barrier, no LDS)
    if (lane == 63) {
        float* ob = out + (size_t)b*OUTPB + (dj*2)*(NH*NK) + h*NK;
        #pragma unroll
        for (int k = 0; k < NK; ++k) ob[k] = cm[k];
        float* oc = ob + NH*NK;
        #pragma unroll
        for (int i = 0; i < 4; ++i) {
            oc[2*i]     = (float)(cp[i] & 0xffffu);
            oc[2*i + 1] = (float)(cp[i] >> 16);
        }
    }
}

extern "C" void kernel_launch(void* const* d_in, const int* in_sizes, int n_in,
                              void* d_out, int out_size, void* d_ws, size_t ws_size,
                              hipStream_t stream) {
    const float* X = (const float*)d_in[0];
    const float* W = (const float*)d_in[1];
    const int*   I = (const int*)d_in[2];
    float* out = (float*)d_out;

    const int nblocks = NB * (NDIL*NDIV) * (NH/4);   // 14336
    hydra_kernel<<<dim3(nblocks), dim3(256), 0, stream>>>(X, W, I, out);
}